// Round 10
// baseline (214.066 us; speedup 1.0000x reference)
//
#include <hip/hip_runtime.h>

#define NB 32
#define NC 128
#define NH 56
#define NW 56
#define HP 58
#define WP 58
#define KK 1152
#define NPOS 3136                         // 56*56
#define XT_BYTES (NB * HP * WP * NC * 2)  // 27,557,888
#define AW_OFF XT_BYTES

typedef __attribute__((ext_vector_type(8))) short s16x8;
typedef __attribute__((ext_vector_type(4))) float f32x4;
typedef unsigned int u32;

__device__ __forceinline__ unsigned short f2bf(float f) {
    union { float f; unsigned int u; } v; v.f = f;
    unsigned int u = v.u + 0x7fffu + ((v.u >> 16) & 1u);
    return (unsigned short)(u >> 16);
}

__device__ __forceinline__ void gld16(const void* g, void* l) {
    __builtin_amdgcn_global_load_lds(
        (const __attribute__((address_space(1))) u32*)g,
        (__attribute__((address_space(3))) u32*)l, 16, 0, 0);
}

// ---- fused prologue (v1 + CENTER-POSITION-keyed chunk swizzle) ----
// xt row (Y,X) stores chunk c at phys c ^ key, key = ((Y-1)*56+(X-1)) & 15.
// Consumer reading tap (dy,dx) at center p uses key (p + dy*56+dx) & 15 —
// affine in p, bijective over any 16 consecutive positions.
__global__ void k_pro(const float* __restrict__ x, const float* __restrict__ w,
                      unsigned short* __restrict__ xt, unsigned short* __restrict__ aw) {
    int blk = blockIdx.x;
    int tid = threadIdx.x;
    if (blk >= 1792) {
        int idx = (blk - 1792) * 256 + tid;   // 589824 total
        if (idx < 512 * KK) {
            int j = idx & 7, lane = (idx >> 3) & 63, mt = (idx >> 9) & 31, s = idx >> 14;
            int m = mt * 16 + (lane & 15);
            int kg = s * 32 + (lane >> 4) * 8 + j;
            int g = kg >> 7, ic = kg & 127;
            aw[idx] = f2bf(w[(m * 128 + ic) * 9 + g]);
        }
        return;
    }
    __shared__ unsigned short tile[128 * 57];
    int b = blk / NH, y = blk % NH;
    const float* xb = x + (size_t)b * (NC * NPOS) + y * NW;
#pragma unroll
    for (int p = 0; p < 7; ++p) {
        int idx = p * 256 + tid;            // 1792 float4 = 7168 floats
        int c = idx / 14, i = idx - c * 14;
        float4 v = *(const float4*)(xb + c * NPOS + i * 4);
        unsigned short* tp = &tile[c * 57 + i * 4];
        tp[0] = f2bf(v.x); tp[1] = f2bf(v.y); tp[2] = f2bf(v.z); tp[3] = f2bf(v.w);
    }
    __syncthreads();
    unsigned short* xrow = xt + ((size_t)(b * HP + y + 1) * WP + 1) * NC;
#pragma unroll
    for (int p = 0; p < 4; ++p) {
        int idx = p * 256 + tid;            // 896 = 56 x-pos * 16 chunks
        if (idx < 896) {
            int xp = idx >> 4, cgi = idx & 15;
            s16x8 v8;
#pragma unroll
            for (int j = 0; j < 8; ++j)
                v8[j] = (short)tile[(cgi * 8 + j) * 57 + xp];
            int key = (y * 56 + xp) & 15;   // center position mod 16
            *(s16x8*)(xrow + xp * NC + ((cgi ^ key) * 8)) = v8;
        }
    }
    if (tid < 128) {
        xt[((size_t)(b * HP + y + 1) * WP + 0) * NC + tid] = 0;
        xt[((size_t)(b * HP + y + 1) * WP + 57) * NC + tid] = 0;
    }
    if (y == 0) {
        unsigned short* r0 = xt + (size_t)(b * HP + 0) * WP * NC;
        for (int i = tid; i < WP * NC; i += 256) r0[i] = 0;
    }
    if (y == 55) {
        unsigned short* r57 = xt + (size_t)(b * HP + 57) * WP * NC;
        for (int i = tid; i < WP * NC; i += 256) r57[i] = 0;
    }
}

// ---- main v10: v9 + head-fragment double-buffer (full-beat LDS cover) ----
// v9 gave every ds_read some MFMA cover but the next-beat head (bfA') only
// got the 12-MFMA tail (~233cy) — marginal vs LDS latency + conflicts.
// v10 ping-pongs the head regs bfP[2][4] (+16 VGPR, compile-time index via
// unrolled j): beat j issues aload -> bfB (tail, 310cy cover) -> bfP[(j+1)&1]
// (next head, 543cy cover) -> 16 head-MFMA on bfP[j&1] -> 12 tail-MFMA.
// Every LDS read now has >=310cy own-wave MFMA between issue and use.
// 144 arch + 112 acc = 256 unified = exactly 2 waves/SIMD (the register
// wall); stage loop stays rolled (v8 proved flattening spills).
__global__ void __launch_bounds__(256, 2) k_main(
    const unsigned short* __restrict__ xt, const unsigned short* __restrict__ aw,
    const float* __restrict__ cwr, const float* __restrict__ cwc,
    const float* __restrict__ brow, const float* __restrict__ bcol,
    const float* __restrict__ bch, float* __restrict__ out) {
    __shared__ __align__(16) unsigned char slab[248 * 256];   // 63,488 B

    const int tid = threadIdx.x;
    const int lane = tid & 63;
    const int wv = tid >> 6;                // 0..3
    const int l15 = lane & 15, quad = lane >> 4;
    const int ph = (wv & 1) * 2;            // per-parity sub-slice rotation
    const int blk = blockIdx.x;
    const int b = blk / 56;
    const int rem = blk - b * 56;
    const int pt = rem >> 1;                // position tile [0,28)
    const int h = rem & 1;                  // channel half
    const int tile0 = pt * 112;
    const int sbase = (pt * 116) & ~15;     // 16-aligned slab start row

    const unsigned char* src = (const unsigned char*)xt
                             + ((size_t)b * (HP * WP) + sbase) * 256;
    // A rows: m = r*128 + h*64 + wv*16 + l15  ->  mt = 8r + 4h + wv
    const unsigned char* gA = (const unsigned char*)aw + (h * 4 + wv) * 1024 + lane * 16;

    // per-lane slab row index (center tap) for each n-subtile
    int R0[7];
#pragma unroll
    for (int t = 0; t < 7; ++t) {
        int pos = tile0 + t * 16 + l15;
        int yy = pos / 56, xx = pos - yy * 56;
        R0[t] = (yy + 1) * WP + (xx + 1) - sbase;
    }

    // stage slab: 3968 x 16B linear copy by 4 waves (tail overreads <=16 rows
    // into the adjacent ws region - allocated, values unused)
#pragma unroll
    for (int i = 0; i < 15; ++i)
        gld16(src + (size_t)(i * 256 + tid) * 16,
              (unsigned char*)slab + (i * 256 + wv * 64) * 16);
    if (tid < 128)
        gld16(src + (size_t)(3840 + tid) * 16,
              (unsigned char*)slab + (3840 + wv * 64) * 16);

    s16x8 Areg[2][4];          // [pingpong][rank]
    f32x4 acc[4][7] = {};      // [rank][ntile]

    auto aload = [&](int s32, int pp) {
#pragma unroll
        for (int r = 0; r < 4; ++r)
            Areg[pp][r] = *(const s16x8*)(gA + s32 * 32768 + r * 8192);
    };

    aload(ph, 0);              // first slice in this wave's rotated sequence
    __syncthreads();           // slab ready (single gld16 drain, outside loop)

    s16x8 bfP[2][4];           // head-fragment ping-pong (compile-time index)
    // prologue: head for beat 0 (st=0: key=(l15+7)&15, kk=ph, toff=-WP-1)
    {
        const int key0 = (l15 + 7) & 15;
        const int coff0 = ((ph * 4 + quad) ^ key0) << 4;
        const int toff0 = -WP - 1;
#pragma unroll
        for (int t = 0; t < 4; ++t)
            bfP[0][t] = *(const s16x8*)((const unsigned char*)slab
                          + ((R0[t] + toff0) << 8) + coff0);
    }

    for (int st = 0; st < 9; ++st) {
        const int dy = (st * 11) >> 5, dxi = st - dy * 3;     // tap coords
        const int toff = (dy - 1) * WP + (dxi - 1);
        const int key = (l15 + (dy - 1) * 56 + (dxi - 1) + 64) & 15;
        const int stn = (st < 8) ? st + 1 : 8;                // next stage
        const int dyn = (stn * 11) >> 5, dxn = stn - dyn * 3;
        const int toffn = (dyn - 1) * WP + (dxn - 1);
        const int keyn = (l15 + (dyn - 1) * 56 + (dxn - 1) + 64) & 15;
#pragma unroll
        for (int j = 0; j < 4; ++j) {
            const int kkw = (j + ph) & 3;
            const bool last = (st == 8) && (j == 3);
            // A for next beat (bank ping-pong, one-beat lead: proven OK)
            if (!last) {
                int nslice = (j < 3) ? st * 4 + (((j + 1) + ph) & 3)
                                     : (st + 1) * 4 + ph;
                aload(nslice, (j + 1) & 1);
            }
            const int coff = ((kkw * 4 + quad) ^ key) << 4;
            // current-beat tail reads (t=4..6): 310cy cover (head MFMA)
            s16x8 bfB[3];
#pragma unroll
            for (int t = 0; t < 3; ++t)
                bfB[t] = *(const s16x8*)((const unsigned char*)slab
                           + ((R0[t + 4] + toff) << 8) + coff);
            // NEXT beat's head reads into the other bank: 543cy cover
            if (!last) {
                const int kkn = (j < 3) ? ((j + 1) + ph) & 3 : ph;
                const int keyx = (j < 3) ? key : keyn;
                const int toffx = (j < 3) ? toff : toffn;
                const int coffn = ((kkn * 4 + quad) ^ keyx) << 4;
#pragma unroll
                for (int t = 0; t < 4; ++t)
                    bfP[(j + 1) & 1][t] = *(const s16x8*)(
                        (const unsigned char*)slab
                        + ((R0[t] + toffx) << 8) + coffn);
            }
            // head-half MFMA on bfP[j&1] (loaded last beat)
            __builtin_amdgcn_s_setprio(1);
#pragma unroll
            for (int r = 0; r < 4; ++r)
#pragma unroll
                for (int t = 0; t < 4; ++t)
                    acc[r][t] = __builtin_amdgcn_mfma_f32_16x16x32_bf16(
                        Areg[j & 1][r], bfP[j & 1][t], acc[r][t], 0, 0, 0);
            __builtin_amdgcn_s_setprio(0);
            // tail-half MFMA on bfB
            __builtin_amdgcn_s_setprio(1);
#pragma unroll
            for (int r = 0; r < 4; ++r)
#pragma unroll
                for (int t = 0; t < 3; ++t)
                    acc[r][t + 4] = __builtin_amdgcn_mfma_f32_16x16x32_bf16(
                        Areg[j & 1][r], bfB[t], acc[r][t + 4], 0, 0, 0);
            __builtin_amdgcn_s_setprio(0);
        }
    }

    // epilogue: inline softmax over rank + combine + biases, fp32 store
#pragma unroll
    for (int t = 0; t < 7; ++t) {
        int pos = tile0 + t * 16 + l15;
        int yy = pos / 56, xx = pos - yy * 56;
        float v0 = cwr[yy]       + cwc[xx];
        float v1 = cwr[56 + yy]  + cwc[56 + xx];
        float v2 = cwr[112 + yy] + cwc[112 + xx];
        float v3 = cwr[168 + yy] + cwc[168 + xx];
        float mx = fmaxf(fmaxf(v0, v1), fmaxf(v2, v3));
        float e0 = __expf(v0 - mx), e1 = __expf(v1 - mx);
        float e2 = __expf(v2 - mx), e3 = __expf(v3 - mx);
        float inv = 1.0f / (e0 + e1 + e2 + e3);
        float c0 = e0 * inv, c1 = e1 * inv, c2 = e2 * inv, c3 = e3 * inv;
        float rb = brow[yy] + bcol[xx];
#pragma unroll
        for (int r = 0; r < 4; ++r) {
            int ch = h * 64 + wv * 16 + quad * 4 + r;
            float v = acc[0][t][r] * c0 + acc[1][t][r] * c1
                    + acc[2][t][r] * c2 + acc[3][t][r] * c3;
            out[((size_t)b * NC + ch) * NPOS + pos] = v + bch[ch] + rb;
        }
    }
}

extern "C" void kernel_launch(void* const* d_in, const int* in_sizes, int n_in,
                              void* d_out, int out_size, void* d_ws, size_t ws_size,
                              hipStream_t stream) {
    const float* x    = (const float*)d_in[0];
    const float* w    = (const float*)d_in[1];
    const float* cwr  = (const float*)d_in[2];
    const float* cwc  = (const float*)d_in[3];
    const float* brow = (const float*)d_in[4];
    const float* bcol = (const float*)d_in[5];
    const float* bch  = (const float*)d_in[6];
    float* out = (float*)d_out;

    unsigned char* ws = (unsigned char*)d_ws;
    unsigned short* xt = (unsigned short*)ws;
    unsigned short* aw = (unsigned short*)(ws + AW_OFF);

    k_pro<<<4096, 256, 0, stream>>>(x, w, xt, aw);   // xpose + wconv fused
    k_main<<<NB * 56, 256, 0, stream>>>(xt, aw, cwr, cwc, brow, bcol, bch, out);
}

// Round 11
// 202.937 us; speedup vs baseline: 1.0548x; 1.0548x over previous
//
#include <hip/hip_runtime.h>

#define NB 32
#define NC 128
#define NH 56
#define NW 56
#define HP 58
#define WP 58
#define KK 1152
#define NPOS 3136                         // 56*56
#define XT_BYTES (NB * HP * WP * NC * 2)  // 27,557,888
#define AW_OFF XT_BYTES

typedef __attribute__((ext_vector_type(8))) short s16x8;
typedef __attribute__((ext_vector_type(4))) float f32x4;
typedef unsigned int u32;

__device__ __forceinline__ unsigned short f2bf(float f) {
    union { float f; unsigned int u; } v; v.f = f;
    unsigned int u = v.u + 0x7fffu + ((v.u >> 16) & 1u);
    return (unsigned short)(u >> 16);
}

__device__ __forceinline__ void gld16(const void* g, void* l) {
    __builtin_amdgcn_global_load_lds(
        (const __attribute__((address_space(1))) u32*)g,
        (__attribute__((address_space(3))) u32*)l, 16, 0, 0);
}

// ---- fused prologue (v1 + CENTER-POSITION-keyed chunk swizzle) ----
// xt row (Y,X) stores chunk c at phys c ^ key, key = ((Y-1)*56+(X-1)) & 15.
// Consumer reading tap (dy,dx) at center p uses key (p + dy*56+dx) & 15 —
// affine in p, bijective over any 16 consecutive positions.
__global__ void k_pro(const float* __restrict__ x, const float* __restrict__ w,
                      unsigned short* __restrict__ xt, unsigned short* __restrict__ aw) {
    int blk = blockIdx.x;
    int tid = threadIdx.x;
    if (blk >= 1792) {
        int idx = (blk - 1792) * 256 + tid;   // 589824 total
        if (idx < 512 * KK) {
            int j = idx & 7, lane = (idx >> 3) & 63, mt = (idx >> 9) & 31, s = idx >> 14;
            int m = mt * 16 + (lane & 15);
            int kg = s * 32 + (lane >> 4) * 8 + j;
            int g = kg >> 7, ic = kg & 127;
            aw[idx] = f2bf(w[(m * 128 + ic) * 9 + g]);
        }
        return;
    }
    __shared__ unsigned short tile[128 * 57];
    int b = blk / NH, y = blk % NH;
    const float* xb = x + (size_t)b * (NC * NPOS) + y * NW;
#pragma unroll
    for (int p = 0; p < 7; ++p) {
        int idx = p * 256 + tid;            // 1792 float4 = 7168 floats
        int c = idx / 14, i = idx - c * 14;
        float4 v = *(const float4*)(xb + c * NPOS + i * 4);
        unsigned short* tp = &tile[c * 57 + i * 4];
        tp[0] = f2bf(v.x); tp[1] = f2bf(v.y); tp[2] = f2bf(v.z); tp[3] = f2bf(v.w);
    }
    __syncthreads();
    unsigned short* xrow = xt + ((size_t)(b * HP + y + 1) * WP + 1) * NC;
#pragma unroll
    for (int p = 0; p < 4; ++p) {
        int idx = p * 256 + tid;            // 896 = 56 x-pos * 16 chunks
        if (idx < 896) {
            int xp = idx >> 4, cgi = idx & 15;
            s16x8 v8;
#pragma unroll
            for (int j = 0; j < 8; ++j)
                v8[j] = (short)tile[(cgi * 8 + j) * 57 + xp];
            int key = (y * 56 + xp) & 15;   // center position mod 16
            *(s16x8*)(xrow + xp * NC + ((cgi ^ key) * 8)) = v8;
        }
    }
    if (tid < 128) {
        xt[((size_t)(b * HP + y + 1) * WP + 0) * NC + tid] = 0;
        xt[((size_t)(b * HP + y + 1) * WP + 57) * NC + tid] = 0;
    }
    if (y == 0) {
        unsigned short* r0 = xt + (size_t)(b * HP + 0) * WP * NC;
        for (int i = tid; i < WP * NC; i += 256) r0[i] = 0;
    }
    if (y == 55) {
        unsigned short* r57 = xt + (size_t)(b * HP + 57) * WP * NC;
        for (int i = tid; i < WP * NC; i += 256) r57[i] = 0;
    }
}

// ---- main v11: exact v9 (best, 116.7us) + XCD-contiguous work remap ----
// v9 schedule untouched: 4-wave 256-thr block, h-half M=256, N=112 slab,
// barrier-free K-loop, beat-granular A ping-pong, intra-beat bfA/bfB split
// (every ds_read has >=233cy own-wave MFMA cover), setprio around MFMA.
// NEW: work_id = (blk%8)*224 + blk/8 (bijective, 1792=8x224): hardware
// round-robins blocks across 8 XCDs, so each XCD now gets 224 CONSECUTIVE
// work-ids = 4 complete batches -> per-XCD xt working set 3.4MB fits its
// private 4MB L2; adjacent pt tiles' halo overlap becomes L2-hit. Shortens
// the A-load / slab-staging latency chains; zero schedule/register change.
__global__ void __launch_bounds__(256, 2) k_main(
    const unsigned short* __restrict__ xt, const unsigned short* __restrict__ aw,
    const float* __restrict__ cwr, const float* __restrict__ cwc,
    const float* __restrict__ brow, const float* __restrict__ bcol,
    const float* __restrict__ bch, float* __restrict__ out) {
    __shared__ __align__(16) unsigned char slab[248 * 256];   // 63,488 B

    const int tid = threadIdx.x;
    const int lane = tid & 63;
    const int wv = tid >> 6;                // 0..3
    const int l15 = lane & 15, quad = lane >> 4;
    const int ph = (wv & 1) * 2;            // per-parity sub-slice rotation
    const int blk = (blockIdx.x & 7) * 224 + (blockIdx.x >> 3);  // XCD-contig
    const int b = blk / 56;
    const int rem = blk - b * 56;
    const int pt = rem >> 1;                // position tile [0,28)
    const int h = rem & 1;                  // channel half
    const int tile0 = pt * 112;
    const int sbase = (pt * 116) & ~15;     // 16-aligned slab start row

    const unsigned char* src = (const unsigned char*)xt
                             + ((size_t)b * (HP * WP) + sbase) * 256;
    // A rows: m = r*128 + h*64 + wv*16 + l15  ->  mt = 8r + 4h + wv
    const unsigned char* gA = (const unsigned char*)aw + (h * 4 + wv) * 1024 + lane * 16;

    // per-lane slab row index (center tap) for each n-subtile
    int R0[7];
#pragma unroll
    for (int t = 0; t < 7; ++t) {
        int pos = tile0 + t * 16 + l15;
        int yy = pos / 56, xx = pos - yy * 56;
        R0[t] = (yy + 1) * WP + (xx + 1) - sbase;
    }

    // stage slab: 3968 x 16B linear copy by 4 waves (tail overreads <=16 rows
    // into the adjacent ws region - allocated, values unused)
#pragma unroll
    for (int i = 0; i < 15; ++i)
        gld16(src + (size_t)(i * 256 + tid) * 16,
              (unsigned char*)slab + (i * 256 + wv * 64) * 16);
    if (tid < 128)
        gld16(src + (size_t)(3840 + tid) * 16,
              (unsigned char*)slab + (3840 + wv * 64) * 16);

    s16x8 Areg[2][4];          // [pingpong][rank]
    f32x4 acc[4][7] = {};      // [rank][ntile]

    auto aload = [&](int s32, int pp) {
#pragma unroll
        for (int r = 0; r < 4; ++r)
            Areg[pp][r] = *(const s16x8*)(gA + s32 * 32768 + r * 8192);
    };

    aload(ph, 0);              // first slice in this wave's rotated sequence
    __syncthreads();           // slab ready (single gld16 drain, outside loop)

    s16x8 bfA[4];
    // prologue: bfA for beat 0 (st=0: D56=-57 -> key=(l15+7)&15; kkw=ph)
    {
        const int key0 = (l15 + 7) & 15;
        const int coff0 = ((ph * 4 + quad) ^ key0) << 4;
        const int toff0 = -WP - 1;
#pragma unroll
        for (int t = 0; t < 4; ++t)
            bfA[t] = *(const s16x8*)((const unsigned char*)slab
                       + ((R0[t] + toff0) << 8) + coff0);
    }

    for (int st = 0; st < 9; ++st) {
        const int dy = (st * 11) >> 5, dxi = st - dy * 3;     // tap coords
        const int toff = (dy - 1) * WP + (dxi - 1);
        const int key = (l15 + (dy - 1) * 56 + (dxi - 1) + 64) & 15;
        const int stn = (st < 8) ? st + 1 : 8;                // next stage
        const int dyn = (stn * 11) >> 5, dxn = stn - dyn * 3;
        const int toffn = (dyn - 1) * WP + (dxn - 1);
        const int keyn = (l15 + (dyn - 1) * 56 + (dxn - 1) + 64) & 15;
#pragma unroll
        for (int j = 0; j < 4; ++j) {
            const int kkw = (j + ph) & 3;
            const bool last = (st == 8) && (j == 3);
            // A for next beat (bank ping-pong, one-beat lead as proven)
            if (!last) {
                int nslice = (j < 3) ? st * 4 + (((j + 1) + ph) & 3)
                                     : (st + 1) * 4 + ph;
                aload(nslice, (j + 1) & 1);
            }
            const int coff = ((kkw * 4 + quad) ^ key) << 4;
            // issue tail-half reads (t=4..6) of current beat
            s16x8 bfB[3];
#pragma unroll
            for (int t = 0; t < 3; ++t)
                bfB[t] = *(const s16x8*)((const unsigned char*)slab
                           + ((R0[t + 4] + toff) << 8) + coff);
            // head-half MFMA on prefetched bfA (covers bfB latency)
            __builtin_amdgcn_s_setprio(1);
#pragma unroll
            for (int r = 0; r < 4; ++r)
#pragma unroll
                for (int t = 0; t < 4; ++t)
                    acc[r][t] = __builtin_amdgcn_mfma_f32_16x16x32_bf16(
                        Areg[j & 1][r], bfA[t], acc[r][t], 0, 0, 0);
            __builtin_amdgcn_s_setprio(0);
            // prefetch next beat's head half (covered by tail-half MFMA)
            if (!last) {
                const int kkn = (j < 3) ? ((j + 1) + ph) & 3 : ph;
                const int keyx = (j < 3) ? key : keyn;
                const int toffx = (j < 3) ? toff : toffn;
                const int coffn = ((kkn * 4 + quad) ^ keyx) << 4;
#pragma unroll
                for (int t = 0; t < 4; ++t)
                    bfA[t] = *(const s16x8*)((const unsigned char*)slab
                               + ((R0[t] + toffx) << 8) + coffn);
            }
            // tail-half MFMA on bfB
            __builtin_amdgcn_s_setprio(1);
#pragma unroll
            for (int r = 0; r < 4; ++r)
#pragma unroll
                for (int t = 0; t < 3; ++t)
                    acc[r][t + 4] = __builtin_amdgcn_mfma_f32_16x16x32_bf16(
                        Areg[j & 1][r], bfB[t], acc[r][t + 4], 0, 0, 0);
            __builtin_amdgcn_s_setprio(0);
        }
    }

    // epilogue: inline softmax over rank + combine + biases, fp32 store
#pragma unroll
    for (int t = 0; t < 7; ++t) {
        int pos = tile0 + t * 16 + l15;
        int yy = pos / 56, xx = pos - yy * 56;
        float v0 = cwr[yy]       + cwc[xx];
        float v1 = cwr[56 + yy]  + cwc[56 + xx];
        float v2 = cwr[112 + yy] + cwc[112 + xx];
        float v3 = cwr[168 + yy] + cwc[168 + xx];
        float mx = fmaxf(fmaxf(v0, v1), fmaxf(v2, v3));
        float e0 = __expf(v0 - mx), e1 = __expf(v1 - mx);
        float e2 = __expf(v2 - mx), e3 = __expf(v3 - mx);
        float inv = 1.0f / (e0 + e1 + e2 + e3);
        float c0 = e0 * inv, c1 = e1 * inv, c2 = e2 * inv, c3 = e3 * inv;
        float rb = brow[yy] + bcol[xx];
#pragma unroll
        for (int r = 0; r < 4; ++r) {
            int ch = h * 64 + wv * 16 + quad * 4 + r;
            float v = acc[0][t][r] * c0 + acc[1][t][r] * c1
                    + acc[2][t][r] * c2 + acc[3][t][r] * c3;
            out[((size_t)b * NC + ch) * NPOS + pos] = v + bch[ch] + rb;
        }
    }
}

extern "C" void kernel_launch(void* const* d_in, const int* in_sizes, int n_in,
                              void* d_out, int out_size, void* d_ws, size_t ws_size,
                              hipStream_t stream) {
    const float* x    = (const float*)d_in[0];
    const float* w    = (const float*)d_in[1];
    const float* cwr  = (const float*)d_in[2];
    const float* cwc  = (const float*)d_in[3];
    const float* brow = (const float*)d_in[4];
    const float* bcol = (const float*)d_in[5];
    const float* bch  = (const float*)d_in[6];
    float* out = (float*)d_out;

    unsigned char* ws = (unsigned char*)d_ws;
    unsigned short* xt = (unsigned short*)ws;
    unsigned short* aw = (unsigned short*)(ws + AW_OFF);

    k_pro<<<4096, 256, 0, stream>>>(x, w, xt, aw);   // xpose + wconv fused
    k_main<<<NB * 56, 256, 0, stream>>>(xt, aw, cwr, cwc, brow, bcol, bch, out);
}